// Round 6
// baseline (314.550 us; speedup 1.0000x reference)
//
#include <hip/hip_runtime.h>
#include <hip/hip_bf16.h>

#define B_ 32
#define S_ 2048
#define D_ 512
#define M_ (B_*S_)   // 65536 rows

typedef __bf16 bf16x8 __attribute__((ext_vector_type(8)));
typedef float  f32x4  __attribute__((ext_vector_type(4)));

__device__ __forceinline__ float tanh_fast(float x){
  float e2 = __expf(2.f * x);                    // inf for large x -> rcp=0 -> 1
  return 1.f - 2.f * __builtin_amdgcn_rcpf(e2 + 1.f);
}

__device__ __forceinline__ bf16x8 pack8(f32x4 r0, f32x4 r1){
  bf16x8 t;
  t[0]=(__bf16)r0[0]; t[1]=(__bf16)r0[1]; t[2]=(__bf16)r0[2]; t[3]=(__bf16)r0[3];
  t[4]=(__bf16)r1[0]; t[5]=(__bf16)r1[1]; t[6]=(__bf16)r1[2]; t[7]=(__bf16)r1[3];
  return t;
}

// async 16B/lane global->LDS DMA (wave-uniform LDS base + lane*16)
__device__ __forceinline__ void gl_lds16(const void* g, void* l){
  __builtin_amdgcn_global_load_lds(
      (const __attribute__((address_space(1))) void*)g,
      (__attribute__((address_space(3))) void*)l, 16, 0, 0);
}

// ---- prep: (a) reorder w_v into bf16 MFMA B-frag order, (b) qproj ----
__global__ void k_prep(const float* __restrict__ wv,
                       unsigned short* __restrict__ wvr,
                       const float* __restrict__ q,
                       const float* __restrict__ wq,
                       const float* __restrict__ bias,
                       float* __restrict__ qp){
  __shared__ float qs[D_];
  __shared__ float red2[2][128];
  int bid = blockIdx.x, t = threadIdx.x;
  if (bid < 128){
    int frag = bid*4 + (t>>6);      // 0..511 ; frag = ks*32 + nt
    int lane = t & 63;
    int ks = frag >> 5, nt = frag & 31;
    int k0 = ks*32 + (lane>>4)*8;
    int d  = nt*16 + (lane&15);
    bf16x8 v;
    #pragma unroll
    for (int j=0;j<8;++j) v[j] = (__bf16)wv[(k0+j)*D_ + d];
    *reinterpret_cast<uint4*>(wvr + ((size_t)frag*64 + lane)*8) =
        __builtin_bit_cast(uint4, v);
  } else {
    int idx = bid - 128;            // 0..127
    int b = idx >> 2, ch = idx & 3;
    int dl = t & 127, eg = t >> 7;  // 2-way K split
    int d  = ch*128 + dl;
    for (int e=t; e<D_; e+=256) qs[e] = q[b*D_+e];
    __syncthreads();
    float a = 0.f;
    #pragma unroll 8
    for (int i=0;i<256;++i){
      int e = eg*256 + i;
      a = fmaf(qs[e], wq[(size_t)e*D_+d], a);
    }
    red2[eg][dl] = a;
    __syncthreads();
    if (eg == 0) qp[b*D_+d] = red2[0][dl] + red2[1][dl] + bias[d];
  }
}

// ---- fused (value@w_v + qproj + loc) -> tanh -> dot(score_w) -> scores ----
// v6: m97 geometry. Block = 128 rows x 128 cols (col-panel cp of 4), 256 thr
// = 4 waves, wave tile 64x64 -> acc[4][4] = 64 AGPRs (3 blocks/CU, 12 w/CU).
// BK=32, double-buffered LDS A (f32, XOR-swizzled 16B units) + B (bf16
// frag-order, linear), both staged via global_load_lds, ONE barrier/step.
// Per-block B traffic 128 KB (was 512 KB). Bijective XCD swizzle puts the
// 4 col-panels of a row-panel consecutively on one XCD -> A re-reads are
// that XCD's L2 hits. Partial scores per 128-col slice; k_softmax sums 4.
__launch_bounds__(256, 3)
__global__ void k_energy(const float* __restrict__ value,
                         const unsigned short* __restrict__ wvr,
                         const float* __restrict__ qp,
                         const float* __restrict__ energy,
                         const float* __restrict__ conv_w,
                         const float* __restrict__ conv_b,
                         const float* __restrict__ score_w,
                         float* __restrict__ sp){
  const int t    = threadIdx.x;
  const int wave = t >> 6;
  const int lane = t & 63;
  const int quad = lane >> 4;
  const int lm   = lane & 15;
  // XCD-bijective work mapping: 2048 blocks, xcd = bid&7 gets work
  // [xcd*256, xcd*256+256) in order -> rp's 4 col-panels adjacent on one XCD.
  const int w    = ((blockIdx.x & 7) << 8) | (blockIdx.x >> 3);
  const int rp   = w >> 2;              // row-panel (128 rows)
  const int cp   = w & 3;               // col-panel (128 cols)
  const int row0 = rp * 128;
  const int b    = row0 >> 11;          // S=2048
  const int s0   = row0 & (S_-1);

  __shared__ __align__(16) float          Abuf[2][4096];   // 2 x 16 KB (128r x 32k f32)
  __shared__ __align__(16) unsigned short Bbuf[2][4096];   // 2 x 8 KB  (8 frags)

  // A DMA: instr j = wave*4+i covers rows j*8..j*8+8 (128B k-slice each).
  // lane l -> row r=j*8+(l>>3), phys 16B-unit p=l&7 holds logical unit p^(r&7).
  int aoff[4];
  #pragma unroll
  for (int i=0;i<4;++i){
    int j = wave*4 + i;
    int r = j*8 + (lane>>3);
    int p = lane & 7;
    aoff[i] = (row0 + r)*D_ + (((p ^ (r&7)) << 2));
  }
  // B DMA: frag j2 = wave*2+i ; global frag f = c*32 + cp*8 + j2 (1KB each)
  const int fb = cp*8 + wave*2;

  f32x4 acc[4][4];
  #pragma unroll
  for (int mt=0;mt<4;++mt)
    #pragma unroll
    for (int n=0;n<4;++n)
      acc[mt][n] = (f32x4){0.f,0.f,0.f,0.f};

  const int mrow = (wave>>1)*64;        // wave rows [mrow, mrow+64)
  const int nco  = (wave&1)*4;          // wave nt base (of block's 8)

  // prologue: stage chunk 0 into buf 0
  #pragma unroll
  for (int i=0;i<4;++i)
    gl_lds16(value + aoff[i], &Abuf[0][(wave*4+i)*256]);
  #pragma unroll
  for (int i=0;i<2;++i)
    gl_lds16(wvr + (size_t)(fb+i)*512 + lane*8, &Bbuf[0][(wave*2+i)*512]);
  __syncthreads();

  for (int c=0;c<16;++c){
    const int buf = c & 1;
    if (c < 15){
      #pragma unroll
      for (int i=0;i<4;++i)
        gl_lds16(value + aoff[i] + (c+1)*32, &Abuf[buf^1][(wave*4+i)*256]);
      #pragma unroll
      for (int i=0;i<2;++i)
        gl_lds16(wvr + ((size_t)((c+1)*32 + fb + i))*512 + lane*8,
                 &Bbuf[buf^1][(wave*2+i)*512]);
    }
    bf16x8 a[4], bq[4];
    #pragma unroll
    for (int mt=0;mt<4;++mt){
      const float* Ab = &Abuf[buf][(mrow + mt*16 + lm)*32];
      f32x4 r0 = *reinterpret_cast<const f32x4*>(Ab + ((((quad<<1)  ) ^ (lm&7))<<2));
      f32x4 r1 = *reinterpret_cast<const f32x4*>(Ab + ((((quad<<1)|1) ^ (lm&7))<<2));
      a[mt] = pack8(r0, r1);
    }
    #pragma unroll
    for (int n=0;n<4;++n)
      bq[n] = __builtin_bit_cast(bf16x8,
          *reinterpret_cast<const uint4*>(&Bbuf[buf][(nco+n)*512 + lane*8]));
    #pragma unroll
    for (int n=0;n<4;++n)
      #pragma unroll
      for (int mt=0;mt<4;++mt)
        acc[mt][n] = __builtin_amdgcn_mfma_f32_16x16x32_bf16(a[mt], bq[n], acc[mt][n], 0,0,0);
    __syncthreads();
  }

  // ---- epilogue: per-lane d = cp*128 + (wave&1)*64 + n*16 + lm ----
  float sw[4], c0[4], c1[4], c2[4], cb[4], qv[4];
  #pragma unroll
  for (int n=0; n<4; ++n){
    int d = cp*128 + (wave&1)*64 + n*16 + lm;
    sw[n] = score_w[d];
    c0[n] = conv_w[d*3+0];
    c1[n] = conv_w[d*3+1];
    c2[n] = conv_w[d*3+2];
    cb[n] = conv_b[d];
    qv[n] = qp[b*D_+d];
  }
  float* red = (float*)&Abuf[0][0];     // [2][128] overlay (post-loop barrier)
  const float* eB = energy + b*S_;
  #pragma unroll
  for (int mt=0; mt<4; ++mt){
    #pragma unroll
    for (int r=0;r<4;++r){
      int sl = mrow + mt*16 + quad*4 + r;       // block-local row 0..127
      int s  = s0 + sl;
      float em1 = (s > 0)    ? eB[s-1] : 0.f;
      float e0  =              eB[s];
      float ep1 = (s < S_-1) ? eB[s+1] : 0.f;
      float p = 0.f;
      #pragma unroll
      for (int n=0; n<4; ++n){
        float h = acc[mt][n][r] + qv[n]
                + fmaf(c0[n],em1, fmaf(c1[n],e0, fmaf(c2[n],ep1, cb[n])));
        p = fmaf(sw[n], tanh_fast(h), p);
      }
      #pragma unroll
      for (int m=1; m<16; m<<=1) p += __shfl_xor(p, m, 64);   // sum 16 cols
      if (lm == 0) red[(wave&1)*128 + sl] = p;
    }
  }
  __syncthreads();
  if (t < 128)
    sp[(size_t)cp*M_ + row0 + t] = red[t] + red[128+t];
}

// ---- softmax over S per batch; sums 4 col-panel partials; zeroes out_ctx ----
__global__ void k_softmax(const float* __restrict__ sp,
                          const float* __restrict__ score_b,
                          float* __restrict__ out_align,
                          float* __restrict__ out_ctx){
  int b = blockIdx.x, t = threadIdx.x;
  int lane = t & 63, wid = t >> 6;
  out_ctx[b*D_ + t]       = 0.f;
  out_ctx[b*D_ + 256 + t] = 0.f;
  float sb = score_b[0];
  float v[8], mx = -3.4e38f;
  #pragma unroll
  for (int i=0;i<8;++i){
    int idx = b*S_ + t + i*256;
    float sc = sp[idx] + sp[M_+idx] + sp[2*M_+idx] + sp[3*M_+idx] + sb;
    v[i] = sc;
    mx = fmaxf(mx, sc);
  }
  __shared__ float red[4], red2[4];
  #pragma unroll
  for (int m=1;m<64;m<<=1) mx = fmaxf(mx, __shfl_xor(mx, m, 64));
  if (lane==0) red[wid] = mx;
  __syncthreads();
  mx = fmaxf(fmaxf(red[0],red[1]), fmaxf(red[2],red[3]));
  float sum = 0.f;
  #pragma unroll
  for (int i=0;i<8;++i){ v[i] = __expf(v[i]-mx); sum += v[i]; }
  #pragma unroll
  for (int m=1;m<64;m<<=1) sum += __shfl_xor(sum, m, 64);
  if (lane==0) red2[wid] = sum;
  __syncthreads();
  sum = red2[0]+red2[1]+red2[2]+red2[3];
  float inv = 1.f/sum;
  #pragma unroll
  for (int i=0;i<8;++i) out_align[b*S_ + t + i*256] = v[i]*inv;
}

// ---- context: block (sc,b) covers 64 s rows; atomicAdd into out_ctx ----
__global__ void k_ctx_part(const float* __restrict__ value,
                           const float* __restrict__ align,
                           float* __restrict__ out_ctx){
  int b = blockIdx.y, sc = blockIdx.x;    // sc 0..31
  int t = threadIdx.x;
  int r = t >> 7;            // 0..1 (s subgroup)
  int c = (t & 127) * 4;     // d base, 4 floats = 16B per thread
  __shared__ float al[64];
  if (t < 64) al[t] = align[b*S_ + sc*64 + t];
  __syncthreads();
  f32x4 acc = (f32x4){0.f,0.f,0.f,0.f};
  const float* vbase = value + ((size_t)(b*S_ + sc*64 + r))*D_ + c;
  #pragma unroll 8
  for (int i=0;i<32;++i){
    f32x4 v = *reinterpret_cast<const f32x4*>(vbase + (size_t)(2*i)*D_);
    acc += al[2*i+r] * v;
  }
  __shared__ float lred[2][D_];
  #pragma unroll
  for (int j=0;j<4;++j) lred[r][c+j] = acc[j];
  __syncthreads();
  if (r == 0){
    #pragma unroll
    for (int j=0;j<4;++j)
      atomicAdd(&out_ctx[(size_t)b*D_ + c + j], lred[0][c+j] + lred[1][c+j]);
  }
}

extern "C" void kernel_launch(void* const* d_in, const int* in_sizes, int n_in,
                              void* d_out, int out_size, void* d_ws, size_t ws_size,
                              hipStream_t stream){
  const float* query   = (const float*)d_in[0];
  const float* value   = (const float*)d_in[1];
  const float* energy  = (const float*)d_in[2];
  const float* conv_w  = (const float*)d_in[3];
  const float* conv_b  = (const float*)d_in[4];
  const float* w_q     = (const float*)d_in[5];
  const float* w_v     = (const float*)d_in[6];
  const float* bias    = (const float*)d_in[7];
  const float* score_w = (const float*)d_in[8];
  const float* score_b = (const float*)d_in[9];

  char* ws = (char*)d_ws;
  unsigned short* wvr = (unsigned short*)(ws);            // 512 KB (bf16 frags)
  float* qp    = (float*)(ws + (512<<10));                // 64 KB
  float* sp    = (float*)(ws + (576<<10));                // 1 MB (4 x 65536 f32)
  // total ~1.6 MB

  float* out_ctx   = (float*)d_out;                       // [B, D] fp32
  float* out_align = out_ctx + B_*D_;                     // [B, S] fp32

  k_prep    <<<dim3(256),      dim3(256), 0, stream>>>(w_v, wvr, query, w_q, bias, qp);
  k_energy  <<<dim3(M_/128*4), dim3(256), 0, stream>>>(value, wvr, qp, energy,
                                                       conv_w, conv_b, score_w, sp);
  k_softmax <<<dim3(B_),       dim3(256), 0, stream>>>(sp, score_b, out_align, out_ctx);
  k_ctx_part<<<dim3(32,B_),    dim3(256), 0, stream>>>(value, out_align, out_ctx);
}

// Round 7
// 298.487 us; speedup vs baseline: 1.0538x; 1.0538x over previous
//
#include <hip/hip_runtime.h>
#include <hip/hip_bf16.h>

#define B_ 32
#define S_ 2048
#define D_ 512
#define M_ (B_*S_)   // 65536 rows

typedef __bf16 bf16x8 __attribute__((ext_vector_type(8)));
typedef float  f32x4  __attribute__((ext_vector_type(4)));

__device__ __forceinline__ float tanh_fast(float x){
  float e2 = __expf(2.f * x);                    // inf for large x -> rcp=0 -> 1
  return 1.f - 2.f * __builtin_amdgcn_rcpf(e2 + 1.f);
}

__device__ __forceinline__ bf16x8 pack8(f32x4 r0, f32x4 r1){
  bf16x8 t;
  t[0]=(__bf16)r0[0]; t[1]=(__bf16)r0[1]; t[2]=(__bf16)r0[2]; t[3]=(__bf16)r0[3];
  t[4]=(__bf16)r1[0]; t[5]=(__bf16)r1[1]; t[6]=(__bf16)r1[2]; t[7]=(__bf16)r1[3];
  return t;
}

// async 16B/lane global->LDS DMA (per-lane global src, wave-uniform LDS base)
__device__ __forceinline__ void gl_lds16(const void* g, void* l){
  __builtin_amdgcn_global_load_lds(
      (const __attribute__((address_space(1))) void*)g,
      (__attribute__((address_space(3))) void*)l, 16, 0, 0);
}

// ---- prep: (a) reorder w_v into bf16 MFMA B-frag order, (b) qproj ----
__global__ void k_prep(const float* __restrict__ wv,
                       unsigned short* __restrict__ wvr,
                       const float* __restrict__ q,
                       const float* __restrict__ wq,
                       const float* __restrict__ bias,
                       float* __restrict__ qp){
  __shared__ float qs[D_];
  __shared__ float red2[2][128];
  int bid = blockIdx.x, t = threadIdx.x;
  if (bid < 128){
    int frag = bid*4 + (t>>6);      // 0..511 ; frag = ks*32 + nt
    int lane = t & 63;
    int ks = frag >> 5, nt = frag & 31;
    int k0 = ks*32 + (lane>>4)*8;
    int d  = nt*16 + (lane&15);
    bf16x8 v;
    #pragma unroll
    for (int j=0;j<8;++j) v[j] = (__bf16)wv[(k0+j)*D_ + d];
    *reinterpret_cast<uint4*>(wvr + ((size_t)frag*64 + lane)*8) =
        __builtin_bit_cast(uint4, v);
  } else {
    int idx = bid - 128;            // 0..127
    int b = idx >> 2, ch = idx & 3;
    int dl = t & 127, eg = t >> 7;  // 2-way K split
    int d  = ch*128 + dl;
    for (int e=t; e<D_; e+=256) qs[e] = q[b*D_+e];
    __syncthreads();
    float a = 0.f;
    #pragma unroll 8
    for (int i=0;i<256;++i){
      int e = eg*256 + i;
      a = fmaf(qs[e], wq[(size_t)e*D_+d], a);
    }
    red2[eg][dl] = a;
    __syncthreads();
    if (eg == 0) qp[b*D_+d] = red2[0][dl] + red2[1][dl] + bias[d];
  }
}

// ---- fused (value@w_v + qproj + loc) -> tanh -> dot(score_w) -> scores ----
// v7: operand-delivery restructure (theory: v2-v6 all limited by LDS/VALU/
// barrier cost of delivering operands, not MFMA/HBM/occupancy).
//  * A: global->REGISTER direct, per consuming wave. No A in LDS, no A
//    conflicts, no staging cvt detour. value is L3-resident; the 2 col-panel
//    blocks per row-panel are XCD-adjacent (swizzle) -> L2 hits.
//  * B: K-quarter resident in LDS, double-buffered (2 x 64KB), DMA'd once
//    per quarter. Reads are linear lane*16B -> conflict-free.
//  * Barriers: 4 per kernel (one per quarter), each phase has 4 chunks of
//    barrier-free ILP, vs 16 drain-barriers in v2-v6.
// Block = 256 rows x 256 cols (cp of 2), 512 thr = 8 waves, wave 64x128,
// acc[4][8] = 128 AGPR -> 2 waves/SIMD, 1 block/CU (128KB LDS). Partial
// scores per 256-col panel summed in k_softmax.
__launch_bounds__(512, 2)
__global__ void k_energy(const float* __restrict__ value,
                         const unsigned short* __restrict__ wvr,
                         const float* __restrict__ qp,
                         const float* __restrict__ energy,
                         const float* __restrict__ conv_w,
                         const float* __restrict__ conv_b,
                         const float* __restrict__ score_w,
                         float* __restrict__ sp){
  const int t    = threadIdx.x;
  const int wave = t >> 6;
  const int lane = t & 63;
  const int quad = lane >> 4;
  const int lm   = lane & 15;
  const int wr   = wave >> 1;           // wave row group (64 rows)
  const int wc   = wave & 1;            // wave col half (128 cols)
  // XCD-bijective: 512 blocks, xcd=bid&7 owns w in [xcd*64, xcd*64+64);
  // consecutive w = same row-panel's 2 col-panels -> same-XCD L2 reuse of A.
  const int w    = ((blockIdx.x & 7) << 6) | (blockIdx.x >> 3);
  const int rp   = w >> 1;              // row-panel (256 rows)
  const int cp   = w & 1;               // col-panel (256 cols)
  const int row0 = rp * 256;
  const int b    = row0 >> 11;          // S=2048, 256|2048 -> single batch
  const int s0   = row0 & (S_-1);

  // B buffers: [buf][frag j=c2*16+nt][lane*8 shorts]; 64 frags x 1KB per buf
  __shared__ __align__(16) unsigned short Blds[2][64*512];   // 128 KB

  // A row-base pointers (per thread): row = row0 + wr*64 + mt*16 + lm, k0 = quad*8
  const float* pA[4];
  #pragma unroll
  for (int mt=0;mt<4;++mt)
    pA[mt] = value + (size_t)(row0 + wr*64 + mt*16 + lm)*D_ + quad*8;

  f32x4 acc[4][8];
  #pragma unroll
  for (int mt=0;mt<4;++mt)
    #pragma unroll
    for (int n=0;n<8;++n)
      acc[mt][n] = (f32x4){0.f,0.f,0.f,0.f};

  // ---- stage quarter 0 into buf 0: wave stages frags j in [wave*8, wave*8+8) ----
  #pragma unroll
  for (int i=0;i<8;++i){
    int j  = wave*8 + i;               // local frag: c2 = j>>4, nt = j&15
    int gf = ((j>>4))*32 + cp*16 + (j&15);          // q4=0
    gl_lds16(wvr + (size_t)gf*512 + lane*8, &Blds[0][j*512]);
  }
  __syncthreads();

  for (int q4=0; q4<4; ++q4){
    const int buf = q4 & 1;
    #pragma unroll
    for (int c=0;c<4;++c){
      const int gc = q4*4 + c;
      // A fragments: 8 x dwordx4 direct from global (imm offsets off pA[mt])
      bf16x8 a[4];
      #pragma unroll
      for (int mt=0;mt<4;++mt){
        f32x4 r0 = *reinterpret_cast<const f32x4*>(pA[mt] + gc*32);
        f32x4 r1 = *reinterpret_cast<const f32x4*>(pA[mt] + gc*32 + 4);
        a[mt] = pack8(r0, r1);
      }
      __builtin_amdgcn_s_setprio(1);
      #pragma unroll
      for (int n=0;n<8;++n){
        bf16x8 bq = __builtin_bit_cast(bf16x8,
            *reinterpret_cast<const uint4*>(&Blds[buf][(c*16 + wc*8 + n)*512 + lane*8]));
        #pragma unroll
        for (int mt=0;mt<4;++mt)
          acc[mt][n] = __builtin_amdgcn_mfma_f32_16x16x32_bf16(a[mt], bq, acc[mt][n], 0,0,0);
      }
      __builtin_amdgcn_s_setprio(0);
      // stage next quarter after first chunk (overlaps with chunks 1..3)
      if (c == 0 && q4 < 3){
        #pragma unroll
        for (int i=0;i<8;++i){
          int j  = wave*8 + i;
          int gf = ((q4+1)*4 + (j>>4))*32 + cp*16 + (j&15);
          gl_lds16(wvr + (size_t)gf*512 + lane*8, &Blds[buf^1][j*512]);
        }
      }
    }
    __syncthreads();   // quarter boundary: staged buf^1 complete, buf free
  }

  // ---- epilogue: per-lane d = cp*256 + wc*128 + n*16 + lm ----
  float sw[8], c0[8], c1[8], c2[8], cb[8], qv[8];
  #pragma unroll
  for (int n=0; n<8; ++n){
    int d = cp*256 + wc*128 + n*16 + lm;
    sw[n] = score_w[d];
    c0[n] = conv_w[d*3+0];
    c1[n] = conv_w[d*3+1];
    c2[n] = conv_w[d*3+2];
    cb[n] = conv_b[d];
    qv[n] = qp[b*D_+d];
  }
  float* red = (float*)&Blds[0][0];    // [2][256] overlay (post-loop barrier)
  const float* eB = energy + b*S_;
  #pragma unroll
  for (int mt=0; mt<4; ++mt){
    #pragma unroll
    for (int r=0;r<4;++r){
      int sl = wr*64 + mt*16 + quad*4 + r;      // block-local row 0..255
      int s  = s0 + sl;
      float em1 = (s > 0)    ? eB[s-1] : 0.f;
      float e0  =              eB[s];
      float ep1 = (s < S_-1) ? eB[s+1] : 0.f;
      float p = 0.f;
      #pragma unroll
      for (int n=0; n<8; ++n){
        float h = acc[mt][n][r] + qv[n]
                + fmaf(c0[n],em1, fmaf(c1[n],e0, fmaf(c2[n],ep1, cb[n])));
        p = fmaf(sw[n], tanh_fast(h), p);
      }
      #pragma unroll
      for (int m=1; m<16; m<<=1) p += __shfl_xor(p, m, 64);   // sum 16 cols
      if (lm == 0) red[wc*256 + sl] = p;
    }
  }
  __syncthreads();
  if (t < 256)
    sp[(size_t)cp*M_ + row0 + t] = red[t] + red[256+t];
}

// ---- softmax over S per batch; sums 2 col-panel partials; zeroes out_ctx ----
__global__ void k_softmax(const float* __restrict__ sp,
                          const float* __restrict__ score_b,
                          float* __restrict__ out_align,
                          float* __restrict__ out_ctx){
  int b = blockIdx.x, t = threadIdx.x;
  int lane = t & 63, wid = t >> 6;
  out_ctx[b*D_ + t]       = 0.f;
  out_ctx[b*D_ + 256 + t] = 0.f;
  float sb = score_b[0];
  float v[8], mx = -3.4e38f;
  #pragma unroll
  for (int i=0;i<8;++i){
    int idx = b*S_ + t + i*256;
    float sc = sp[idx] + sp[M_+idx] + sb;
    v[i] = sc;
    mx = fmaxf(mx, sc);
  }
  __shared__ float red[4], red2[4];
  #pragma unroll
  for (int m=1;m<64;m<<=1) mx = fmaxf(mx, __shfl_xor(mx, m, 64));
  if (lane==0) red[wid] = mx;
  __syncthreads();
  mx = fmaxf(fmaxf(red[0],red[1]), fmaxf(red[2],red[3]));
  float sum = 0.f;
  #pragma unroll
  for (int i=0;i<8;++i){ v[i] = __expf(v[i]-mx); sum += v[i]; }
  #pragma unroll
  for (int m=1;m<64;m<<=1) sum += __shfl_xor(sum, m, 64);
  if (lane==0) red2[wid] = sum;
  __syncthreads();
  sum = red2[0]+red2[1]+red2[2]+red2[3];
  float inv = 1.f/sum;
  #pragma unroll
  for (int i=0;i<8;++i) out_align[b*S_ + t + i*256] = v[i]*inv;
}

// ---- context: block (sc,b) covers 64 s rows; atomicAdd into out_ctx ----
__global__ void k_ctx_part(const float* __restrict__ value,
                           const float* __restrict__ align,
                           float* __restrict__ out_ctx){
  int b = blockIdx.y, sc = blockIdx.x;    // sc 0..31
  int t = threadIdx.x;
  int r = t >> 7;            // 0..1 (s subgroup)
  int c = (t & 127) * 4;     // d base, 4 floats = 16B per thread
  __shared__ float al[64];
  if (t < 64) al[t] = align[b*S_ + sc*64 + t];
  __syncthreads();
  f32x4 acc = (f32x4){0.f,0.f,0.f,0.f};
  const float* vbase = value + ((size_t)(b*S_ + sc*64 + r))*D_ + c;
  #pragma unroll 8
  for (int i=0;i<32;++i){
    f32x4 v = *reinterpret_cast<const f32x4*>(vbase + (size_t)(2*i)*D_);
    acc += al[2*i+r] * v;
  }
  __shared__ float lred[2][D_];
  #pragma unroll
  for (int j=0;j<4;++j) lred[r][c+j] = acc[j];
  __syncthreads();
  if (r == 0){
    #pragma unroll
    for (int j=0;j<4;++j)
      atomicAdd(&out_ctx[(size_t)b*D_ + c + j], lred[0][c+j] + lred[1][c+j]);
  }
}

extern "C" void kernel_launch(void* const* d_in, const int* in_sizes, int n_in,
                              void* d_out, int out_size, void* d_ws, size_t ws_size,
                              hipStream_t stream){
  const float* query   = (const float*)d_in[0];
  const float* value   = (const float*)d_in[1];
  const float* energy  = (const float*)d_in[2];
  const float* conv_w  = (const float*)d_in[3];
  const float* conv_b  = (const float*)d_in[4];
  const float* w_q     = (const float*)d_in[5];
  const float* w_v     = (const float*)d_in[6];
  const float* bias    = (const float*)d_in[7];
  const float* score_w = (const float*)d_in[8];
  const float* score_b = (const float*)d_in[9];

  char* ws = (char*)d_ws;
  unsigned short* wvr = (unsigned short*)(ws);            // 512 KB (bf16 frags)
  float* qp    = (float*)(ws + (512<<10));                // 64 KB
  float* sp    = (float*)(ws + (576<<10));                // 512 KB (2 x 65536 f32)
  // total ~1.1 MB

  float* out_ctx   = (float*)d_out;                       // [B, D] fp32
  float* out_align = out_ctx + B_*D_;                     // [B, S] fp32

  k_prep    <<<dim3(256),   dim3(256), 0, stream>>>(w_v, wvr, query, w_q, bias, qp);
  k_energy  <<<dim3(512),   dim3(512), 0, stream>>>(value, wvr, qp, energy,
                                                    conv_w, conv_b, score_w, sp);
  k_softmax <<<dim3(B_),    dim3(256), 0, stream>>>(sp, score_b, out_align, out_ctx);
  k_ctx_part<<<dim3(32,B_), dim3(256), 0, stream>>>(value, out_align, out_ctx);
}

// Round 8
// 262.937 us; speedup vs baseline: 1.1963x; 1.1352x over previous
//
#include <hip/hip_runtime.h>
#include <hip/hip_bf16.h>

#define B_ 32
#define S_ 2048
#define D_ 512
#define M_ (B_*S_)   // 65536 rows

typedef __bf16 bf16x8 __attribute__((ext_vector_type(8)));
typedef float  f32x4  __attribute__((ext_vector_type(4)));

__device__ __forceinline__ float tanh_fast(float x){
  float e2 = __expf(2.f * x);                    // inf for large x -> rcp=0 -> 1
  return 1.f - 2.f * __builtin_amdgcn_rcpf(e2 + 1.f);
}

// ---- prep: (a) reorder w_v into bf16 MFMA B-frag order, (b) qproj ----
__global__ void k_prep(const float* __restrict__ wv,
                       unsigned short* __restrict__ wvr,
                       const float* __restrict__ q,
                       const float* __restrict__ wq,
                       const float* __restrict__ bias,
                       float* __restrict__ qp){
  __shared__ float qs[D_];
  __shared__ float red2[2][128];
  int bid = blockIdx.x, t = threadIdx.x;
  if (bid < 128){
    int frag = bid*4 + (t>>6);      // 0..511 ; frag = ks*32 + nt
    int lane = t & 63;
    int ks = frag >> 5, nt = frag & 31;
    int k0 = ks*32 + (lane>>4)*8;
    int d  = nt*16 + (lane&15);
    bf16x8 v;
    #pragma unroll
    for (int j=0;j<8;++j) v[j] = (__bf16)wv[(k0+j)*D_ + d];
    *reinterpret_cast<uint4*>(wvr + ((size_t)frag*64 + lane)*8) =
        __builtin_bit_cast(uint4, v);
  } else {
    int idx = bid - 128;            // 0..127
    int b = idx >> 2, ch = idx & 3;
    int dl = t & 127, eg = t >> 7;  // 2-way K split
    int d  = ch*128 + dl;
    for (int e=t; e<D_; e+=256) qs[e] = q[b*D_+e];
    __syncthreads();
    float a = 0.f;
    #pragma unroll 8
    for (int i=0;i<256;++i){
      int e = eg*256 + i;
      a = fmaf(qs[e], wq[(size_t)e*D_+d], a);
    }
    red2[eg][dl] = a;
    __syncthreads();
    if (eg == 0) qp[b*D_+d] = red2[0][dl] + red2[1][dl] + bias[d];
  }
}

// ---- fused (value@w_v + qproj + loc) -> tanh -> scores -> LOCAL softmax
//      -> partial context (flash-style) ----
// Core GEMM = v2 structure (best measured, 79.8us): 64-row block, 4 waves,
// wave d-span 128 (acc[4][8]), BK=64 period, reg-dbuf B frags, LDS A stage.
// NEW epilogue: block computes m_blk, e_s=exp(score-m_blk), l_blk, and
// pc[d] = sum_s e_s * value[s,d] from L2-hot rows -> kills the 128MB
// second pass over value that k_ctx_part did (the ~190us elephant).
__launch_bounds__(256, 2)
__global__ void k_energy(const float* __restrict__ value,
                         const unsigned short* __restrict__ wvr,
                         const float* __restrict__ qp,
                         const float* __restrict__ energy,
                         const float* __restrict__ conv_w,
                         const float* __restrict__ conv_b,
                         const float* __restrict__ score_w,
                         float* __restrict__ sp,
                         float* __restrict__ cpart,
                         float* __restrict__ mArr,
                         float* __restrict__ lArr){
  const int t    = threadIdx.x;
  const int wave = t >> 6;
  const int lane = t & 63;
  const int quad = lane >> 4;
  const int lm   = lane & 15;
  const int row0 = blockIdx.x * 64;
  const int b    = row0 >> 11;          // S=2048
  const int s0   = row0 & (S_-1);

  // As[buf][half][mt][o*16+r][8]: frag-ordered A, 64 rows x 64 k bf16 per buf
  __shared__ __align__(16) unsigned short As[2][2][4][64][8];   // 16 KB

  // staging: thread t -> row sr = t>>2, k-octet so = t&3 (within 32-half)
  const int sr  = t >> 2;
  const int so  = t & 3;
  const float* gA = value + (size_t)(row0+sr)*D_ + so*8;
  unsigned short* wA = &As[0][0][sr>>4][so*16 + (sr&15)][0];
  // strides in shorts: half = 2048, buf = 4096

  f32x4 acc[4][8];
  #pragma unroll
  for (int mt=0;mt<4;++mt)
    #pragma unroll
    for (int nt=0;nt<8;++nt)
      acc[mt][nt] = (f32x4){0.f,0.f,0.f,0.f};

  const unsigned short* bP = wvr + ((size_t)(wave*8)*64 + lane)*8;

  bf16x8 bcur[8], bnxt[8];
  #pragma unroll
  for (int n=0;n<8;++n)
    bcur[n] = __builtin_bit_cast(bf16x8,
        *reinterpret_cast<const uint4*>(bP + (size_t)n*512));
  {
    f32x4 p0 = *reinterpret_cast<const f32x4*>(gA);
    f32x4 p1 = *reinterpret_cast<const f32x4*>(gA + 4);
    f32x4 p2 = *reinterpret_cast<const f32x4*>(gA + 32);
    f32x4 p3 = *reinterpret_cast<const f32x4*>(gA + 36);
    bf16x8 t0, t1;
    t0[0]=(__bf16)p0[0]; t0[1]=(__bf16)p0[1]; t0[2]=(__bf16)p0[2]; t0[3]=(__bf16)p0[3];
    t0[4]=(__bf16)p1[0]; t0[5]=(__bf16)p1[1]; t0[6]=(__bf16)p1[2]; t0[7]=(__bf16)p1[3];
    t1[0]=(__bf16)p2[0]; t1[1]=(__bf16)p2[1]; t1[2]=(__bf16)p2[2]; t1[3]=(__bf16)p2[3];
    t1[4]=(__bf16)p3[0]; t1[5]=(__bf16)p3[1]; t1[6]=(__bf16)p3[2]; t1[7]=(__bf16)p3[3];
    *reinterpret_cast<uint4*>(wA)        = __builtin_bit_cast(uint4, t0);
    *reinterpret_cast<uint4*>(wA + 2048) = __builtin_bit_cast(uint4, t1);
  }
  __syncthreads();

  for (int p=0; p<8; ++p){
    const int buf = p & 1;
    unsigned short* wAp = wA + (buf^1)*4096;

    f32x4 n0, n1, n2, n3;
    if (p < 7){
      const float* g = gA + (p+1)*64;
      n0 = *reinterpret_cast<const f32x4*>(g);
      n1 = *reinterpret_cast<const f32x4*>(g + 4);
      n2 = *reinterpret_cast<const f32x4*>(g + 32);
      n3 = *reinterpret_cast<const f32x4*>(g + 36);
    }

    #pragma unroll
    for (int n=0;n<8;++n)
      bnxt[n] = __builtin_bit_cast(bf16x8,
          *reinterpret_cast<const uint4*>(bP + (size_t)((2*p+1)*32+n)*512));

    {
      bf16x8 a[4];
      #pragma unroll
      for (int mt=0;mt<4;++mt)
        a[mt] = *reinterpret_cast<const bf16x8*>(&As[buf][0][mt][lane][0]);
      #pragma unroll
      for (int ntl=0;ntl<8;++ntl)
        #pragma unroll
        for (int mt=0;mt<4;++mt)
          acc[mt][ntl] = __builtin_amdgcn_mfma_f32_16x16x32_bf16(a[mt], bcur[ntl], acc[mt][ntl], 0,0,0);
    }

    if (p < 7){
      #pragma unroll
      for (int n=0;n<8;++n)
        bcur[n] = __builtin_bit_cast(bf16x8,
            *reinterpret_cast<const uint4*>(bP + (size_t)((2*p+2)*32+n)*512));
    }

    {
      bf16x8 a[4];
      #pragma unroll
      for (int mt=0;mt<4;++mt)
        a[mt] = *reinterpret_cast<const bf16x8*>(&As[buf][1][mt][lane][0]);
      #pragma unroll
      for (int ntl=0;ntl<8;++ntl)
        #pragma unroll
        for (int mt=0;mt<4;++mt)
          acc[mt][ntl] = __builtin_amdgcn_mfma_f32_16x16x32_bf16(a[mt], bnxt[ntl], acc[mt][ntl], 0,0,0);
    }

    if (p < 7){
      bf16x8 t0, t1;
      t0[0]=(__bf16)n0[0]; t0[1]=(__bf16)n0[1]; t0[2]=(__bf16)n0[2]; t0[3]=(__bf16)n0[3];
      t0[4]=(__bf16)n1[0]; t0[5]=(__bf16)n1[1]; t0[6]=(__bf16)n1[2]; t0[7]=(__bf16)n1[3];
      t1[0]=(__bf16)n2[0]; t1[1]=(__bf16)n2[1]; t1[2]=(__bf16)n2[2]; t1[3]=(__bf16)n2[3];
      t1[4]=(__bf16)n3[0]; t1[5]=(__bf16)n3[1]; t1[6]=(__bf16)n3[2]; t1[7]=(__bf16)n3[3];
      *reinterpret_cast<uint4*>(wAp)        = __builtin_bit_cast(uint4, t0);
      *reinterpret_cast<uint4*>(wAp + 2048) = __builtin_bit_cast(uint4, t1);
    }
    __syncthreads();
  }

  // ---- scores epilogue: per-lane d set = wave*128 + ntl*16 + lm ----
  float sw[8], c0[8], c1[8], c2[8], cb[8], qv[8];
  #pragma unroll
  for (int ntl=0; ntl<8; ++ntl){
    int d = wave*128 + ntl*16 + lm;
    sw[ntl] = score_w[d];
    c0[ntl] = conv_w[d*3+0];
    c1[ntl] = conv_w[d*3+1];
    c2[ntl] = conv_w[d*3+2];
    cb[ntl] = conv_b[d];
    qv[ntl] = qp[b*D_+d];
  }
  float* red  = (float*)&As[0][0][0][0][0];   // 256 floats
  float* sArr = red + 256;                    // 64 scores
  float* eArr = red + 320;                    // 64 exp-weights
  const float* eB = energy + b*S_;
  #pragma unroll
  for (int mt=0; mt<4; ++mt){
    #pragma unroll
    for (int r=0;r<4;++r){
      int sl = mt*16 + quad*4 + r;              // C/D layout: row=quad*4+reg
      int s  = s0 + sl;
      float em1 = (s > 0)    ? eB[s-1] : 0.f;
      float e0  =              eB[s];
      float ep1 = (s < S_-1) ? eB[s+1] : 0.f;
      float p = 0.f;
      #pragma unroll
      for (int ntl=0; ntl<8; ++ntl){
        float h = acc[mt][ntl][r] + qv[ntl]
                + fmaf(c0[ntl],em1, fmaf(c1[ntl],e0, fmaf(c2[ntl],ep1, cb[ntl])));
        p = fmaf(sw[ntl], tanh_fast(h), p);
      }
      #pragma unroll
      for (int m=1; m<16; m<<=1) p += __shfl_xor(p, m, 64);   // reduce 16 cols
      if (lm == 0) red[wave*64 + sl] = p;
    }
  }
  __syncthreads();
  if (t < 64){
    float sv = red[t] + red[64+t] + red[128+t] + red[192+t];
    sp[row0 + t] = sv;
    sArr[t] = sv;
  }
  __syncthreads();

  // ---- local softmax (m, e_s, l) ----
  if (wave == 0){
    float m = sArr[lane];
    #pragma unroll
    for (int mm=1; mm<64; mm<<=1) m = fmaxf(m, __shfl_xor(m, mm, 64));
    float e = __expf(sArr[lane] - m);
    eArr[lane] = e;
    float l = e;
    #pragma unroll
    for (int mm=1; mm<64; mm<<=1) l += __shfl_xor(l, mm, 64);
    if (lane == 0){ mArr[blockIdx.x] = m; lArr[blockIdx.x] = l; }
  }
  __syncthreads();

  // ---- partial context: pc[d] = sum_s e_s * value[row0+s, d] (L2-hot) ----
  float a0 = 0.f, a1 = 0.f;
  const float* vb = value + (size_t)row0*D_;
  #pragma unroll 8
  for (int s2=0; s2<64; ++s2){
    float wgt = eArr[s2];
    a0 = fmaf(wgt, vb[(size_t)s2*D_ + t],       a0);
    a1 = fmaf(wgt, vb[(size_t)s2*D_ + t + 256], a1);
  }
  cpart[(size_t)blockIdx.x*D_ + t]       = a0;
  cpart[(size_t)blockIdx.x*D_ + t + 256] = a1;
}

// ---- final: per batch, combine 32 block-partials; write align + ctx ----
__global__ void k_final(const float* __restrict__ sp,
                        const float* __restrict__ mArr,
                        const float* __restrict__ lArr,
                        const float* __restrict__ cpart,
                        float* __restrict__ out_align,
                        float* __restrict__ out_ctx){
  int b = blockIdx.x, t = threadIdx.x;    // 256 thr
  __shared__ float wArr[32];
  __shared__ float Msh, Lsh;
  if (t < 32){
    float m = mArr[b*32 + t];
    float M = m;
    #pragma unroll
    for (int mm=1; mm<32; mm<<=1) M = fmaxf(M, __shfl_xor(M, mm, 64));
    float w = __expf(m - M);
    float l = lArr[b*32 + t] * w;
    float L = l;
    #pragma unroll
    for (int mm=1; mm<32; mm<<=1) L += __shfl_xor(L, mm, 64);
    wArr[t] = w;
    if (t == 0){ Msh = M; Lsh = L; }
  }
  __syncthreads();
  float M = Msh, invL = 1.f / Lsh;
  #pragma unroll
  for (int i=0;i<8;++i){
    int s = t + i*256;
    out_align[b*S_ + s] = __expf(sp[b*S_ + s] - M) * invL;
  }
  float a0 = 0.f, a1 = 0.f;
  const float* cp = cpart + (size_t)b*32*D_;
  #pragma unroll
  for (int i=0;i<32;++i){
    float w = wArr[i];
    a0 = fmaf(w, cp[(size_t)i*D_ + t],       a0);
    a1 = fmaf(w, cp[(size_t)i*D_ + t + 256], a1);
  }
  out_ctx[b*D_ + t]       = a0 * invL;
  out_ctx[b*D_ + 256 + t] = a1 * invL;
}

extern "C" void kernel_launch(void* const* d_in, const int* in_sizes, int n_in,
                              void* d_out, int out_size, void* d_ws, size_t ws_size,
                              hipStream_t stream){
  const float* query   = (const float*)d_in[0];
  const float* value   = (const float*)d_in[1];
  const float* energy  = (const float*)d_in[2];
  const float* conv_w  = (const float*)d_in[3];
  const float* conv_b  = (const float*)d_in[4];
  const float* w_q     = (const float*)d_in[5];
  const float* w_v     = (const float*)d_in[6];
  const float* bias    = (const float*)d_in[7];
  const float* score_w = (const float*)d_in[8];
  const float* score_b = (const float*)d_in[9];
  (void)score_b;   // softmax shift-invariance: score_b cancels exactly

  char* ws = (char*)d_ws;
  unsigned short* wvr = (unsigned short*)(ws);            // 512 KB (bf16 frags)
  float* qp    = (float*)(ws + (512<<10));                // 64 KB
  float* sp    = (float*)(ws + (576<<10));                // 256 KB (65536 f32)
  float* cpart = (float*)(ws + (832<<10));                // 2 MB (1024 x 512 f32)
  float* mArr  = (float*)(ws + (2880<<10));               // 4 KB
  float* lArr  = (float*)(ws + (2884<<10));               // 4 KB
  // total ~2.9 MB

  float* out_ctx   = (float*)d_out;                       // [B, D] fp32
  float* out_align = out_ctx + B_*D_;                     // [B, S] fp32

  k_prep  <<<dim3(256),   dim3(256), 0, stream>>>(w_v, wvr, query, w_q, bias, qp);
  k_energy<<<dim3(M_/64), dim3(256), 0, stream>>>(value, wvr, qp, energy,
                                                  conv_w, conv_b, score_w,
                                                  sp, cpart, mArr, lArr);
  k_final <<<dim3(B_),    dim3(256), 0, stream>>>(sp, mArr, lArr, cpart,
                                                  out_align, out_ctx);
}

// Round 9
// 256.222 us; speedup vs baseline: 1.2276x; 1.0262x over previous
//
#include <hip/hip_runtime.h>
#include <hip/hip_bf16.h>

#define B_ 32
#define S_ 2048
#define D_ 512
#define M_ (B_*S_)   // 65536 rows

typedef __bf16 bf16x8 __attribute__((ext_vector_type(8)));
typedef float  f32x4  __attribute__((ext_vector_type(4)));

__device__ __forceinline__ float tanh_fast(float x){
  float e2 = __expf(2.f * x);                    // inf for large x -> rcp=0 -> 1
  return 1.f - 2.f * __builtin_amdgcn_rcpf(e2 + 1.f);
}

// ---- prep: (a) reorder w_v into bf16 MFMA B-frag order, (b) qproj ----
__global__ void k_prep(const float* __restrict__ wv,
                       unsigned short* __restrict__ wvr,
                       const float* __restrict__ q,
                       const float* __restrict__ wq,
                       const float* __restrict__ bias,
                       float* __restrict__ qp){
  __shared__ float qs[D_];
  __shared__ float red2[2][128];
  int bid = blockIdx.x, t = threadIdx.x;
  if (bid < 128){
    int frag = bid*4 + (t>>6);      // 0..511 ; frag = ks*32 + nt
    int lane = t & 63;
    int ks = frag >> 5, nt = frag & 31;
    int k0 = ks*32 + (lane>>4)*8;
    int d  = nt*16 + (lane&15);
    bf16x8 v;
    #pragma unroll
    for (int j=0;j<8;++j) v[j] = (__bf16)wv[(k0+j)*D_ + d];
    *reinterpret_cast<uint4*>(wvr + ((size_t)frag*64 + lane)*8) =
        __builtin_bit_cast(uint4, v);
  } else {
    int idx = bid - 128;            // 0..127
    int b = idx >> 2, ch = idx & 3;
    int dl = t & 127, eg = t >> 7;  // 2-way K split
    int d  = ch*128 + dl;
    for (int e=t; e<D_; e+=256) qs[e] = q[b*D_+e];
    __syncthreads();
    float a = 0.f;
    #pragma unroll 8
    for (int i=0;i<256;++i){
      int e = eg*256 + i;
      a = fmaf(qs[e], wq[(size_t)e*D_+d], a);
    }
    red2[eg][dl] = a;
    __syncthreads();
    if (eg == 0) qp[b*D_+d] = red2[0][dl] + red2[1][dl] + bias[d];
  }
}

// ---- fused (value@w_v + qproj + loc) -> tanh -> scores -> LOCAL softmax
//      -> partial context from the LDS-RESIDENT V tile ----
// v9: v2's GEMM pipeline (79.8us measured), but the staged A tile (= this
// block's 64x512 slice of value, bf16 frag-order) stays resident: 8 period
// slots x 8KB = 64KB LDS, staging writes slot p+1 while computing slot p
// (same barrier count as the 2-slot dbuf). The flash pc-epilogue then reads
// V from LDS -- kills v8's 57MB HBM refetch (FETCH 127->71MB) and its
// latency-bound global pc loop. Score scratch moved to separate LDS (no
// aliasing with live V). pc reads staggered by lane>>2 so banks =
// 4*(r%8)+(lane&3) -> 2 lanes/bank (free); eArr reads are 4-lane broadcasts.
__launch_bounds__(256, 2)
__global__ void k_energy(const float* __restrict__ value,
                         const unsigned short* __restrict__ wvr,
                         const float* __restrict__ qp,
                         const float* __restrict__ energy,
                         const float* __restrict__ conv_w,
                         const float* __restrict__ conv_b,
                         const float* __restrict__ score_w,
                         float* __restrict__ sp,
                         float* __restrict__ cpart,
                         float* __restrict__ mArr,
                         float* __restrict__ lArr){
  const int t    = threadIdx.x;
  const int wave = t >> 6;
  const int lane = t & 63;
  const int quad = lane >> 4;
  const int lm   = lane & 15;
  const int row0 = blockIdx.x * 64;
  const int b    = row0 >> 11;          // S=2048
  const int s0   = row0 & (S_-1);

  // As[period][half][mt][o*16+r][8]: V[row0+mt*16+r][p*64+h*32+o*8+j], 64 KB
  __shared__ __align__(16) unsigned short As[8][2][4][64][8];
  __shared__ float red[256 + 128];      // red[256] | sArr[64] | eArr[64]
  float* sArr = red + 256;
  float* eArr = red + 320;

  // staging: thread t -> row sr = t>>2, k-octet so = t&3 (within 32-half)
  const int sr  = t >> 2;
  const int so  = t & 3;
  const float* gA = value + (size_t)(row0+sr)*D_ + so*8;
  unsigned short* wA = &As[0][0][sr>>4][so*16 + (sr&15)][0];
  // strides in shorts: half = 2048, period slot = 4096

  f32x4 acc[4][8];
  #pragma unroll
  for (int mt=0;mt<4;++mt)
    #pragma unroll
    for (int nt=0;nt<8;++nt)
      acc[mt][nt] = (f32x4){0.f,0.f,0.f,0.f};

  const unsigned short* bP = wvr + ((size_t)(wave*8)*64 + lane)*8;

  bf16x8 bcur[8], bnxt[8];
  #pragma unroll
  for (int n=0;n<8;++n)
    bcur[n] = __builtin_bit_cast(bf16x8,
        *reinterpret_cast<const uint4*>(bP + (size_t)n*512));
  {
    f32x4 p0 = *reinterpret_cast<const f32x4*>(gA);
    f32x4 p1 = *reinterpret_cast<const f32x4*>(gA + 4);
    f32x4 p2 = *reinterpret_cast<const f32x4*>(gA + 32);
    f32x4 p3 = *reinterpret_cast<const f32x4*>(gA + 36);
    bf16x8 t0, t1;
    t0[0]=(__bf16)p0[0]; t0[1]=(__bf16)p0[1]; t0[2]=(__bf16)p0[2]; t0[3]=(__bf16)p0[3];
    t0[4]=(__bf16)p1[0]; t0[5]=(__bf16)p1[1]; t0[6]=(__bf16)p1[2]; t0[7]=(__bf16)p1[3];
    t1[0]=(__bf16)p2[0]; t1[1]=(__bf16)p2[1]; t1[2]=(__bf16)p2[2]; t1[3]=(__bf16)p2[3];
    t1[4]=(__bf16)p3[0]; t1[5]=(__bf16)p3[1]; t1[6]=(__bf16)p3[2]; t1[7]=(__bf16)p3[3];
    *reinterpret_cast<uint4*>(wA)        = __builtin_bit_cast(uint4, t0);
    *reinterpret_cast<uint4*>(wA + 2048) = __builtin_bit_cast(uint4, t1);
  }
  __syncthreads();

  for (int p=0; p<8; ++p){
    unsigned short* wAp = wA + (p+1)*4096;    // next period's slot

    f32x4 n0, n1, n2, n3;
    if (p < 7){
      const float* g = gA + (p+1)*64;
      n0 = *reinterpret_cast<const f32x4*>(g);
      n1 = *reinterpret_cast<const f32x4*>(g + 4);
      n2 = *reinterpret_cast<const f32x4*>(g + 32);
      n3 = *reinterpret_cast<const f32x4*>(g + 36);
    }

    #pragma unroll
    for (int n=0;n<8;++n)
      bnxt[n] = __builtin_bit_cast(bf16x8,
          *reinterpret_cast<const uint4*>(bP + (size_t)((2*p+1)*32+n)*512));

    {
      bf16x8 a[4];
      #pragma unroll
      for (int mt=0;mt<4;++mt)
        a[mt] = *reinterpret_cast<const bf16x8*>(&As[p][0][mt][lane][0]);
      #pragma unroll
      for (int ntl=0;ntl<8;++ntl)
        #pragma unroll
        for (int mt=0;mt<4;++mt)
          acc[mt][ntl] = __builtin_amdgcn_mfma_f32_16x16x32_bf16(a[mt], bcur[ntl], acc[mt][ntl], 0,0,0);
    }

    if (p < 7){
      #pragma unroll
      for (int n=0;n<8;++n)
        bcur[n] = __builtin_bit_cast(bf16x8,
            *reinterpret_cast<const uint4*>(bP + (size_t)((2*p+2)*32+n)*512));
    }

    {
      bf16x8 a[4];
      #pragma unroll
      for (int mt=0;mt<4;++mt)
        a[mt] = *reinterpret_cast<const bf16x8*>(&As[p][1][mt][lane][0]);
      #pragma unroll
      for (int ntl=0;ntl<8;++ntl)
        #pragma unroll
        for (int mt=0;mt<4;++mt)
          acc[mt][ntl] = __builtin_amdgcn_mfma_f32_16x16x32_bf16(a[mt], bnxt[ntl], acc[mt][ntl], 0,0,0);
    }

    if (p < 7){
      bf16x8 t0, t1;
      t0[0]=(__bf16)n0[0]; t0[1]=(__bf16)n0[1]; t0[2]=(__bf16)n0[2]; t0[3]=(__bf16)n0[3];
      t0[4]=(__bf16)n1[0]; t0[5]=(__bf16)n1[1]; t0[6]=(__bf16)n1[2]; t0[7]=(__bf16)n1[3];
      t1[0]=(__bf16)n2[0]; t1[1]=(__bf16)n2[1]; t1[2]=(__bf16)n2[2]; t1[3]=(__bf16)n2[3];
      t1[4]=(__bf16)n3[0]; t1[5]=(__bf16)n3[1]; t1[6]=(__bf16)n3[2]; t1[7]=(__bf16)n3[3];
      *reinterpret_cast<uint4*>(wAp)        = __builtin_bit_cast(uint4, t0);
      *reinterpret_cast<uint4*>(wAp + 2048) = __builtin_bit_cast(uint4, t1);
    }
    __syncthreads();
  }

  // ---- scores epilogue: per-lane d set = wave*128 + ntl*16 + lm ----
  float sw[8], c0[8], c1[8], c2[8], cb[8], qv[8];
  #pragma unroll
  for (int ntl=0; ntl<8; ++ntl){
    int d = wave*128 + ntl*16 + lm;
    sw[ntl] = score_w[d];
    c0[ntl] = conv_w[d*3+0];
    c1[ntl] = conv_w[d*3+1];
    c2[ntl] = conv_w[d*3+2];
    cb[ntl] = conv_b[d];
    qv[ntl] = qp[b*D_+d];
  }
  const float* eB = energy + b*S_;
  #pragma unroll
  for (int mt=0; mt<4; ++mt){
    #pragma unroll
    for (int r=0;r<4;++r){
      int sl = mt*16 + quad*4 + r;              // C/D layout: row=quad*4+reg
      int s  = s0 + sl;
      float em1 = (s > 0)    ? eB[s-1] : 0.f;
      float e0  =              eB[s];
      float ep1 = (s < S_-1) ? eB[s+1] : 0.f;
      float p = 0.f;
      #pragma unroll
      for (int ntl=0; ntl<8; ++ntl){
        float h = acc[mt][ntl][r] + qv[ntl]
                + fmaf(c0[ntl],em1, fmaf(c1[ntl],e0, fmaf(c2[ntl],ep1, cb[ntl])));
        p = fmaf(sw[ntl], tanh_fast(h), p);
      }
      #pragma unroll
      for (int m=1; m<16; m<<=1) p += __shfl_xor(p, m, 64);   // reduce 16 cols
      if (lm == 0) red[wave*64 + sl] = p;
    }
  }
  __syncthreads();
  if (t < 64){
    float sv = red[t] + red[64+t] + red[128+t] + red[192+t];
    sp[row0 + t] = sv;
    sArr[t] = sv;
  }
  __syncthreads();

  // ---- local softmax (m, e_s, l) ----
  if (wave == 0){
    float m = sArr[lane];
    #pragma unroll
    for (int mm=1; mm<64; mm<<=1) m = fmaxf(m, __shfl_xor(m, mm, 64));
    float e = __expf(sArr[lane] - m);
    eArr[lane] = e;
    float l = e;
    #pragma unroll
    for (int mm=1; mm<64; mm<<=1) l += __shfl_xor(l, mm, 64);
    if (lane == 0){ mArr[blockIdx.x] = m; lArr[blockIdx.x] = l; }
  }
  __syncthreads();

  // ---- partial context from LDS V tile: pc[d] = sum_s e_s * V[s,d] ----
  // thread t covers d0=2t, d0+1 (one b32 = both bf16). s-walk staggered by
  // lane>>2: bank = 4*((s&15)%8) + (lane&3) -> 2 lanes/bank (conflict-free).
  {
    const int d0 = 2*t;
    const int pp = d0 >> 6, hh = (d0 >> 5) & 1, oo = (d0 >> 3) & 3, jj = d0 & 7;
    const unsigned short* vb = &As[pp][hh][0][oo*16][jj];   // + mt*512 + r*8
    float a0 = 0.f, a1 = 0.f;
    const int l4 = lane >> 2;
    for (int i=0; i<16; ++i){
      int r = (l4 + i) & 15;
      #pragma unroll
      for (int mt=0; mt<4; ++mt){
        float e = eArr[mt*16 + r];
        unsigned int w = *reinterpret_cast<const unsigned int*>(vb + mt*512 + r*8);
        float lo = __builtin_bit_cast(float, w << 16);
        float hi = __builtin_bit_cast(float, w & 0xffff0000u);
        a0 = fmaf(e, lo, a0);
        a1 = fmaf(e, hi, a1);
      }
    }
    cpart[(size_t)blockIdx.x*D_ + d0]     = a0;
    cpart[(size_t)blockIdx.x*D_ + d0 + 1] = a1;
  }
}

// ---- final: per batch, combine 32 block-partials; write align + ctx ----
__global__ void k_final(const float* __restrict__ sp,
                        const float* __restrict__ mArr,
                        const float* __restrict__ lArr,
                        const float* __restrict__ cpart,
                        float* __restrict__ out_align,
                        float* __restrict__ out_ctx){
  int b = blockIdx.x, t = threadIdx.x;    // 256 thr
  __shared__ float wArr[32];
  __shared__ float Msh, Lsh;
  if (t < 32){
    float m = mArr[b*32 + t];
    float M = m;
    #pragma unroll
    for (int mm=1; mm<32; mm<<=1) M = fmaxf(M, __shfl_xor(M, mm, 64));
    float w = __expf(m - M);
    float l = lArr[b*32 + t] * w;
    float L = l;
    #pragma unroll
    for (int mm=1; mm<32; mm<<=1) L += __shfl_xor(L, mm, 64);
    wArr[t] = w;
    if (t == 0){ Msh = M; Lsh = L; }
  }
  __syncthreads();
  float M = Msh, invL = 1.f / Lsh;
  #pragma unroll
  for (int i=0;i<8;++i){
    int s = t + i*256;
    out_align[b*S_ + s] = __expf(sp[b*S_ + s] - M) * invL;
  }
  float a0 = 0.f, a1 = 0.f;
  const float* cp = cpart + (size_t)b*32*D_;
  #pragma unroll
  for (int i=0;i<32;++i){
    float w = wArr[i];
    a0 = fmaf(w, cp[(size_t)i*D_ + t],       a0);
    a1 = fmaf(w, cp[(size_t)i*D_ + t + 256], a1);
  }
  out_ctx[b*D_ + t]       = a0 * invL;
  out_ctx[b*D_ + 256 + t] = a1 * invL;
}

extern "C" void kernel_launch(void* const* d_in, const int* in_sizes, int n_in,
                              void* d_out, int out_size, void* d_ws, size_t ws_size,
                              hipStream_t stream){
  const float* query   = (const float*)d_in[0];
  const float* value   = (const float*)d_in[1];
  const float* energy  = (const float*)d_in[2];
  const float* conv_w  = (const float*)d_in[3];
  const float* conv_b  = (const float*)d_in[4];
  const float* w_q     = (const float*)d_in[5];
  const float* w_v     = (const float*)d_in[6];
  const float* bias    = (const float*)d_in[7];
  const float* score_w = (const float*)d_in[8];
  const float* score_b = (const float*)d_in[9];
  (void)score_b;   // softmax shift-invariance: score_b cancels exactly

  char* ws = (char*)d_ws;
  unsigned short* wvr = (unsigned short*)(ws);            // 512 KB (bf16 frags)
  float* qp    = (float*)(ws + (512<<10));                // 64 KB
  float* sp    = (float*)(ws + (576<<10));                // 256 KB (65536 f32)
  float* cpart = (float*)(ws + (832<<10));                // 2 MB (1024 x 512 f32)
  float* mArr  = (float*)(ws + (2880<<10));               // 4 KB
  float* lArr  = (float*)(ws + (2884<<10));               // 4 KB
  // total ~2.9 MB

  float* out_ctx   = (float*)d_out;                       // [B, D] fp32
  float* out_align = out_ctx + B_*D_;                     // [B, S] fp32

  k_prep  <<<dim3(256),   dim3(256), 0, stream>>>(w_v, wvr, query, w_q, bias, qp);
  k_energy<<<dim3(M_/64), dim3(256), 0, stream>>>(value, wvr, qp, energy,
                                                  conv_w, conv_b, score_w,
                                                  sp, cpart, mArr, lArr);
  k_final <<<dim3(B_),    dim3(256), 0, stream>>>(sp, mArr, lArr, cpart,
                                                  out_align, out_ctx);
}